// Round 2
// baseline (43.316 us; speedup 1.0000x reference)
//
#include <hip/hip_runtime.h>
#include <math.h>

#define RR 8192   // rows
#define FF 4096   // features
#define LL 2048   // gather length
#define RPB 8     // rows per block
#define TPB 256   // threads per block
#define NBLK (RR / RPB)   // 1024 blocks

// ---------------- kernel 1: fused wsum-scatter + gemv(k,v) + per-block softmax partial ----------------
__global__ __launch_bounds__(TPB) void fused_main(const float* __restrict__ in,
                                                  const int* __restrict__ idx,
                                                  const float* __restrict__ wts,
                                                  float* __restrict__ partials /* [NBLK][3] */) {
    __shared__ float w1s[FF];            // 16 KB: wsum for k
    __shared__ float w2s[FF];            // 16 KB: wsum for v
    __shared__ float redbuf[4][RPB * 2];
    __shared__ float qred[4];
    __shared__ float kvrow[RPB * 2];

    const int t = threadIdx.x, lane = t & 63, wv = t >> 6;
    const int r0 = blockIdx.x * RPB;

    // --- phase A: zero LDS wsum, scatter weights, gather q_last ---
    for (int i = t; i < FF; i += TPB) { w1s[i] = 0.f; w2s[i] = 0.f; }
    __syncthreads();

    const float* lastrow = in + (size_t)(RR - 1) * FF;
    float qp = 0.f;
#pragma unroll
    for (int l = t; l < LL; l += TPB) {          // 8 iterations, coalesced idx
        const int c = idx[l];
        const float x0 = wts[3 * l + 0];
        const float x1 = wts[3 * l + 1];
        const float x2 = wts[3 * l + 2];
        qp += lastrow[c] * x0;                   // same FP order in every block -> deterministic
        atomicAdd(&w1s[c], x1);
        atomicAdd(&w2s[c], x2);
    }
    for (int o = 32; o > 0; o >>= 1) qp += __shfl_down(qp, o);
    if (lane == 0) qred[wv] = qp;
    __syncthreads();                              // also fences all LDS atomics
    const float q = qred[0] + qred[1] + qred[2] + qred[3];

    // --- phase B: k,v = inputs[r0:r0+8] @ {w1s,w2s} ---
    float acc[RPB][2];
#pragma unroll
    for (int r = 0; r < RPB; ++r) { acc[r][0] = 0.f; acc[r][1] = 0.f; }

#pragma unroll
    for (int i = 0; i < FF; i += TPB * 4) {
        const int c = i + t * 4;
        const float4 a1 = *(const float4*)&w1s[c];
        const float4 a2 = *(const float4*)&w2s[c];
#pragma unroll
        for (int r = 0; r < RPB; ++r) {
            const float4 x = *(const float4*)(in + (size_t)(r0 + r) * FF + c);
            acc[r][0] += x.x * a1.x + x.y * a1.y + x.z * a1.z + x.w * a1.w;
            acc[r][1] += x.x * a2.x + x.y * a2.y + x.z * a2.z + x.w * a2.w;
        }
    }

    // block-wide reduce each row's (k,v)
#pragma unroll
    for (int r = 0; r < RPB; ++r)
#pragma unroll
        for (int j = 0; j < 2; ++j)
            for (int o = 32; o > 0; o >>= 1)
                acc[r][j] += __shfl_down(acc[r][j], o);

    if (lane == 0) {
#pragma unroll
        for (int r = 0; r < RPB; ++r) {
            redbuf[wv][r * 2 + 0] = acc[r][0];
            redbuf[wv][r * 2 + 1] = acc[r][1];
        }
    }
    __syncthreads();
    if (t < RPB * 2) kvrow[t] = redbuf[0][t] + redbuf[1][t] + redbuf[2][t] + redbuf[3][t];
    __syncthreads();

    // --- phase C: per-block online-softmax partial over its 8 rows ---
    if (t == 0) {
        float m = -INFINITY;
#pragma unroll
        for (int r = 0; r < RPB; ++r) m = fmaxf(m, q * kvrow[r * 2 + 0]);
        float se = 0.f, sv = 0.f;
#pragma unroll
        for (int r = 0; r < RPB; ++r) {
            const float e = expf(q * kvrow[r * 2 + 0] - m);
            se += e;
            sv += e * kvrow[r * 2 + 1];
        }
        partials[blockIdx.x * 3 + 0] = m;
        partials[blockIdx.x * 3 + 1] = se;
        partials[blockIdx.x * 3 + 2] = sv;
    }
}

// ---------------- kernel 2: merge partials -> sigmoid ----------------
__global__ __launch_bounds__(TPB) void combine(const float* __restrict__ partials,
                                               float* __restrict__ out) {
    const int t = threadIdx.x, lane = t & 63, wv = t >> 6;
    float lm[NBLK / TPB], lse[NBLK / TPB], lsv[NBLK / TPB];
    float m = -INFINITY;
#pragma unroll
    for (int i = 0; i < NBLK / TPB; ++i) {
        const int b = t + i * TPB;
        lm[i]  = partials[b * 3 + 0];
        lse[i] = partials[b * 3 + 1];
        lsv[i] = partials[b * 3 + 2];
        m = fmaxf(m, lm[i]);
    }

    __shared__ float red[4], red2[4], red3[4], bcast[1];
    for (int o = 32; o > 0; o >>= 1) m = fmaxf(m, __shfl_down(m, o));
    if (lane == 0) red[wv] = m;
    __syncthreads();
    if (t == 0) bcast[0] = fmaxf(fmaxf(red[0], red[1]), fmaxf(red[2], red[3]));
    __syncthreads();
    const float gm = bcast[0];

    float se = 0.f, sv = 0.f;
#pragma unroll
    for (int i = 0; i < NBLK / TPB; ++i) {
        const float s = expf(lm[i] - gm);
        se += lse[i] * s;
        sv += lsv[i] * s;
    }
    for (int o = 32; o > 0; o >>= 1) { se += __shfl_down(se, o); sv += __shfl_down(sv, o); }
    if (lane == 0) { red2[wv] = se; red3[wv] = sv; }
    __syncthreads();
    if (t == 0) {
        const float S = red2[0] + red2[1] + red2[2] + red2[3];
        const float V = red3[0] + red3[1] + red3[2] + red3[3];
        const float val = V / S;
        out[0] = 1.0f / (1.0f + expf(-val));
    }
}

extern "C" void kernel_launch(void* const* d_in, const int* in_sizes, int n_in,
                              void* d_out, int out_size, void* d_ws, size_t ws_size,
                              hipStream_t stream) {
    const float* inputs = (const float*)d_in[0];
    const int*   idx    = (const int*)d_in[1];
    const float* wts    = (const float*)d_in[2];
    float* out      = (float*)d_out;
    float* partials = (float*)d_ws;   // NBLK*3 floats = 12 KB

    fused_main<<<NBLK, TPB, 0, stream>>>(inputs, idx, wts, partials);
    combine<<<1, TPB, 0, stream>>>(partials, out);
}

// Round 3
// 35.546 us; speedup vs baseline: 1.2186x; 1.2186x over previous
//
#include <hip/hip_runtime.h>
#include <math.h>

#define RR 8192   // rows
#define FF 4096   // features
#define LL 2048   // gather length
#define RPB 8     // rows per block (one per wave)
#define NBLK (RR / RPB)   // 1024 blocks in main kernel

// ws layout: [0..FF) w1 | [FF..2FF) w2 | [2FF] q | [2FF+1 .. 2FF+1+3*NBLK) partials
#define WS_W1 0
#define WS_W2 FF
#define WS_Q  (2 * FF)
#define WS_P  (2 * FF + 1)

// ---------------- kernel 1: prep (1 block) ----------------
// builds dense wsum for k,v in LDS -> global; computes q = qkv[last,0] directly
__global__ __launch_bounds__(1024) void prep(const float* __restrict__ in,
                                             const int* __restrict__ idx,
                                             const float* __restrict__ wts,
                                             float* __restrict__ ws) {
    __shared__ float w1s[FF];
    __shared__ float w2s[FF];
    __shared__ float qred[16];

    const int t = threadIdx.x, lane = t & 63, wv = t >> 6;

    for (int i = t; i < FF; i += 1024) { w1s[i] = 0.f; w2s[i] = 0.f; }
    __syncthreads();

    const float* lastrow = in + (size_t)(RR - 1) * FF;
    float qp = 0.f;
#pragma unroll
    for (int l = t; l < LL; l += 1024) {        // 2 iterations
        const int c = idx[l];
        qp += lastrow[c] * wts[3 * l + 0];
        atomicAdd(&w1s[c], wts[3 * l + 1]);
        atomicAdd(&w2s[c], wts[3 * l + 2]);
    }
    for (int o = 32; o > 0; o >>= 1) qp += __shfl_down(qp, o);
    if (lane == 0) qred[wv] = qp;
    __syncthreads();                             // fences LDS atomics too

    // write dense wsum (coalesced float4) + q
    if (t < FF / 4) {
        *(float4*)(ws + WS_W1 + t * 4) = *(const float4*)&w1s[t * 4];
        *(float4*)(ws + WS_W2 + t * 4) = *(const float4*)&w2s[t * 4];
    }
    if (t == 0) {
        float q = 0.f;
#pragma unroll
        for (int i = 0; i < 16; ++i) q += qred[i];
        ws[WS_Q] = q;
    }
}

// ---------------- kernel 2: wave-per-row GEMV(k,v) + per-block softmax partial ----------------
__global__ __launch_bounds__(512) void gemv_kv(const float* __restrict__ in,
                                               const float* __restrict__ ws,
                                               float* __restrict__ partials) {
    const int t = threadIdx.x, lane = t & 63, wv = t >> 6;
    const int row = blockIdx.x * RPB + wv;
    const float* __restrict__ x  = in + (size_t)row * FF;
    const float* __restrict__ w1 = ws + WS_W1;
    const float* __restrict__ w2 = ws + WS_W2;

    float k = 0.f, v = 0.f;
#pragma unroll
    for (int i = 0; i < FF; i += 256) {          // 16 independent float4 loads per wave
        const int c = i + lane * 4;
        const float4 xv = *(const float4*)(x + c);
        const float4 a1 = *(const float4*)(w1 + c);
        const float4 a2 = *(const float4*)(w2 + c);
        k += xv.x * a1.x + xv.y * a1.y + xv.z * a1.z + xv.w * a1.w;
        v += xv.x * a2.x + xv.y * a2.y + xv.z * a2.z + xv.w * a2.w;
    }
    for (int o = 32; o > 0; o >>= 1) { k += __shfl_down(k, o); v += __shfl_down(v, o); }

    __shared__ float kv[RPB][2];
    if (lane == 0) { kv[wv][0] = k; kv[wv][1] = v; }
    __syncthreads();

    if (t == 0) {
        const float q = ws[WS_Q];
        float m = -INFINITY;
#pragma unroll
        for (int r = 0; r < RPB; ++r) m = fmaxf(m, q * kv[r][0]);
        float se = 0.f, sv = 0.f;
#pragma unroll
        for (int r = 0; r < RPB; ++r) {
            const float e = expf(q * kv[r][0] - m);
            se += e;
            sv += e * kv[r][1];
        }
        partials[blockIdx.x * 3 + 0] = m;
        partials[blockIdx.x * 3 + 1] = se;
        partials[blockIdx.x * 3 + 2] = sv;
    }
}

// ---------------- kernel 3: merge partials -> sigmoid ----------------
__global__ __launch_bounds__(256) void combine(const float* __restrict__ partials,
                                               float* __restrict__ out) {
    const int t = threadIdx.x, lane = t & 63, wv = t >> 6;
    float lm[NBLK / 256], lse[NBLK / 256], lsv[NBLK / 256];
    float m = -INFINITY;
#pragma unroll
    for (int i = 0; i < NBLK / 256; ++i) {
        const int b = t + i * 256;
        lm[i]  = partials[b * 3 + 0];
        lse[i] = partials[b * 3 + 1];
        lsv[i] = partials[b * 3 + 2];
        m = fmaxf(m, lm[i]);
    }

    __shared__ float red[4], red2[4], red3[4], bcast[1];
    for (int o = 32; o > 0; o >>= 1) m = fmaxf(m, __shfl_down(m, o));
    if (lane == 0) red[wv] = m;
    __syncthreads();
    if (t == 0) bcast[0] = fmaxf(fmaxf(red[0], red[1]), fmaxf(red[2], red[3]));
    __syncthreads();
    const float gm = bcast[0];

    float se = 0.f, sv = 0.f;
#pragma unroll
    for (int i = 0; i < NBLK / 256; ++i) {
        const float s = expf(lm[i] - gm);
        se += lse[i] * s;
        sv += lsv[i] * s;
    }
    for (int o = 32; o > 0; o >>= 1) { se += __shfl_down(se, o); sv += __shfl_down(sv, o); }
    if (lane == 0) { red2[wv] = se; red3[wv] = sv; }
    __syncthreads();
    if (t == 0) {
        const float S = red2[0] + red2[1] + red2[2] + red2[3];
        const float V = red3[0] + red3[1] + red3[2] + red3[3];
        const float val = V / S;
        out[0] = 1.0f / (1.0f + expf(-val));
    }
}

extern "C" void kernel_launch(void* const* d_in, const int* in_sizes, int n_in,
                              void* d_out, int out_size, void* d_ws, size_t ws_size,
                              hipStream_t stream) {
    const float* inputs = (const float*)d_in[0];
    const int*   idx    = (const int*)d_in[1];
    const float* wts    = (const float*)d_in[2];
    float* out = (float*)d_out;
    float* ws  = (float*)d_ws;

    prep<<<1, 1024, 0, stream>>>(inputs, idx, wts, ws);
    gemv_kv<<<NBLK, 512, 0, stream>>>(inputs, ws, ws + WS_P);
    combine<<<1, 256, 0, stream>>>(ws + WS_P, out);
}